// Round 10
// baseline (600.706 us; speedup 1.0000x reference)
//
#include <hip/hip_runtime.h>

#define N_NODES 100000
#define N_EDGES 3200000
#define N_GRAPHS 2048
#define BSH 6                       // phase-1: 64 dst nodes per bucket
#define BSZ 64
#define NB 1563                     // ceil(100000/64)
#define FILL_BLOCKS 512
#define CHUNK 6250                  // N_EDGES / FILL_BLOCKS
#define DBLK 512                    // dst nodes per block (8 buckets)
#define NBD 196                     // ceil(100000/512)
#define SSH 9
#define SSZ 512                     // src nodes per slice
#define NSS 196                     // ceil(100000/512)
#define NPAD (NBD * DBLK)           // 100352
#define SPLIT 4                     // slice-parallel blocks per dst-block

// ---------- phase 1: bucket sort by dst (proven machinery) ----------
__global__ void k_count(const int* __restrict__ dst, int* __restrict__ bcnt,
                        int* __restrict__ blockBase) {
  __shared__ int hist[NB];
  int tid = threadIdx.x, blk = blockIdx.x;
  for (int i = tid; i < NB; i += 256) hist[i] = 0;
  __syncthreads();
  int beg = blk * CHUNK, end = beg + CHUNK;
  for (int e = beg + tid; e < end; e += 256) atomicAdd(&hist[dst[e] >> BSH], 1);
  __syncthreads();
  for (int i = tid; i < NB; i += 256) {
    int h = hist[i];
    if (h) blockBase[blk * NB + i] = atomicAdd(&bcnt[i], h);
  }
}

__global__ void k_bscan(const int* __restrict__ bcnt, int* __restrict__ boffs) {
  __shared__ int sh[512];
  __shared__ int carry;
  int tid = threadIdx.x;
  if (tid == 0) carry = 0;
  __syncthreads();
  for (int c = 0; c < NB; c += 512) {
    int i = c + tid;
    int v = (i < NB) ? bcnt[i] : 0;
    sh[tid] = v;
    __syncthreads();
    for (int off = 1; off < 512; off <<= 1) {
      int t = (tid >= off) ? sh[tid - off] : 0;
      __syncthreads();
      sh[tid] += t;
      __syncthreads();
    }
    if (i < NB) boffs[i] = carry + sh[tid] - v;
    __syncthreads();
    if (tid == 511) carry += sh[511];
    __syncthreads();
  }
  if (tid == 0) boffs[NB] = N_EDGES;
}

__global__ void k_fill(const int* __restrict__ src, const int* __restrict__ dst,
                       const int* __restrict__ boffs, const int* __restrict__ blockBase,
                       unsigned* __restrict__ stage1) {
  __shared__ int lbase[NB];
  int tid = threadIdx.x, blk = blockIdx.x;
  for (int i = tid; i < NB; i += 256) lbase[i] = boffs[i] + blockBase[blk * NB + i];
  __syncthreads();
  int beg = blk * CHUNK, end = beg + CHUNK;
  for (int e = beg + tid; e < end; e += 256) {
    int d = dst[e], s = src[e];
    int pos = atomicAdd(&lbase[d >> BSH], 1);
    stage1[pos] = ((unsigned)s << BSH) | (unsigned)(d & (BSZ - 1));  // src:17 | dstloc:6
  }
}

// ---------- phase 2: per dst-block, sort edges by src-slice ----------
__global__ void k_sort2(const unsigned* __restrict__ stage1, const int* __restrict__ boffs,
                        unsigned* __restrict__ stage2, int* __restrict__ toffs) {
  __shared__ int hist[NSS], curs[NSS], scanbuf[256], splits[9];
  int blk = blockIdx.x, tid = threadIdx.x;
  if (tid <= 8) {
    int bi = blk * 8 + tid;
    splits[tid] = boffs[bi > NB ? NB : bi];
  }
  for (int i = tid; i < NSS; i += 256) hist[i] = 0;
  __syncthreads();
  int segbeg = splits[0], segend = splits[8];
  for (int k = segbeg + tid; k < segend; k += 256)
    atomicAdd(&hist[(stage1[k] >> BSH) >> SSH], 1);
  __syncthreads();
  int v = (tid < NSS) ? hist[tid] : 0;
  scanbuf[tid] = v;
  __syncthreads();
  for (int off = 1; off < 256; off <<= 1) {
    int t = (tid >= off) ? scanbuf[tid - off] : 0;
    __syncthreads();
    scanbuf[tid] += t;
    __syncthreads();
  }
  if (tid < NSS) {
    int o = segbeg + scanbuf[tid] - v;
    curs[tid] = o;
    toffs[blk * NSS + tid] = o;
  }
  if (blk == NBD - 1 && tid == 0) toffs[NBD * NSS] = N_EDGES;
  __syncthreads();
  for (int k = segbeg + tid; k < segend; k += 256) {
    unsigned u = stage1[k];
    int s = u >> BSH;
    int t = s >> SSH;
    int b = 0;
#pragma unroll
    for (int j = 1; j < 8; j++) b += (k >= splits[j]);
    int pos = atomicAdd(&curs[t], 1);
    stage2[pos] = ((unsigned)(s & (SSZ - 1)) << 9) | (unsigned)(b * 64 + (u & 63));
  }
}

// ---------- dinv + padded xd8 = x*dinv ----------
__global__ void k_prep(const unsigned* __restrict__ stage1, const int* __restrict__ boffs,
                       const float* __restrict__ x, float* __restrict__ dinv,
                       float* __restrict__ xd8) {
  __shared__ int cnt[BSZ];
  int b = blockIdx.x, tid = threadIdx.x;
  if (tid < BSZ) cnt[tid] = 0;
  __syncthreads();
  int beg = boffs[b], end = boffs[b + 1];
  for (int k = beg + tid; k < end; k += 256) atomicAdd(&cnt[stage1[k] & (BSZ - 1)], 1);
  __syncthreads();
  int node = b * BSZ + tid;
  if (tid < BSZ && node < N_NODES) {
    float di = rsqrtf((float)(cnt[tid] + 1));     // +1 self-loop
    dinv[node] = di;
    float r[5];
#pragma unroll
    for (int c = 0; c < 5; c++) r[c] = x[node * 5 + c] * di;
    float4* xv = (float4*)xd8;
    xv[node * 2]     = make_float4(r[0], r[1], r[2], r[3]);
    xv[node * 2 + 1] = make_float4(r[4], 0.f, 0.f, 0.f);
  }
}

// ---------- tiled aggregation: stream src-slices through LDS, accumulate in LDS ----------
template <int NC>
__global__ void k_aggt(const unsigned* __restrict__ stage2, const int* __restrict__ toffs,
                       const float* __restrict__ tab, float* __restrict__ partial) {
  __shared__ float slice[SSZ * 12];               // stride 12: float4-aligned, banks ok
  __shared__ float acc[DBLK * 9];                 // stride 9: banks spread
  int bx = blockIdx.x;
  int blk = bx >> 2, p = bx & (SPLIT - 1);
  int tid = threadIdx.x;
  for (int i = tid; i < DBLK * 9; i += 256) acc[i] = 0.f;
  for (int t = p; t < NSS; t += SPLIT) {
    __syncthreads();                              // slice reuse barrier
    int base = t << SSH;
    for (int f = tid; f < SSZ * 2; f += 256) {    // coalesced stream: 16B/lane
      int r = f >> 1, h = f & 1;
      int row = base + r;
      float4 v = (row < N_NODES) ? ((const float4*)(tab + (size_t)row * 8))[h]
                                 : make_float4(0.f, 0.f, 0.f, 0.f);
      *(float4*)(slice + r * 12 + h * 4) = v;
    }
    __syncthreads();
    int beg = toffs[blk * NSS + t], end = toffs[blk * NSS + t + 1];
    for (int k = beg + tid; k < end; k += 256) {
      unsigned u = stage2[k];
      const float* sp = slice + (u >> 9) * 12;
      float* ap = acc + (u & 511) * 9;
#pragma unroll
      for (int c = 0; c < NC; c++) atomicAdd(ap + c, sp[c]);
    }
  }
  __syncthreads();
  float* pa = partial + ((size_t)p * NPAD + (size_t)blk * DBLK) * 8;
  for (int i = tid; i < DBLK * 8; i += 256)
    pa[i] = acc[(i >> 3) * 9 + (i & 7)];
}

// ---------- layer-1 epilogue: merge partials + self-loop, fused MLP -> g2 ----------
__global__ void k_mlp(const float* __restrict__ partial, const float* __restrict__ xd8,
                      const float* __restrict__ dinv, const float* __restrict__ W1,
                      const float* __restrict__ b1, const float* __restrict__ W2,
                      float* __restrict__ g2) {
  __shared__ float w1[150], bb1[30], w2[240];
  int tid = threadIdx.x;
  for (int i = tid; i < 150; i += 256) w1[i] = W1[i];
  for (int i = tid; i < 30; i += 256) bb1[i] = b1[i];
  for (int i = tid; i < 240; i += 256) w2[i] = W2[i];
  __syncthreads();
  int n = blockIdx.x * 256 + tid;
  if (n >= N_NODES) return;
  float di = dinv[n];
  float t[5];
#pragma unroll
  for (int c = 0; c < 5; c++) {
    float s = xd8[n * 8 + c];
#pragma unroll
    for (int p = 0; p < SPLIT; p++) s += partial[((size_t)p * NPAD + n) * 8 + c];
    t[c] = s * di;
  }
  float h[30];
#pragma unroll
  for (int j = 0; j < 30; j++) h[j] = bb1[j];
#pragma unroll
  for (int k = 0; k < 5; k++)
#pragma unroll
    for (int j = 0; j < 30; j++) h[j] += t[k] * w1[k * 30 + j];
  float g[8] = {0, 0, 0, 0, 0, 0, 0, 0};
#pragma unroll
  for (int j = 0; j < 30; j++) {
    float hj = fmaxf(h[j], 0.f);
#pragma unroll
    for (int c = 0; c < 8; c++) g[c] += hj * w2[j * 8 + c];
  }
  float4* gv = (float4*)g2;
  gv[n * 2]     = make_float4(g[0] * di, g[1] * di, g[2] * di, g[3] * di);
  gv[n * 2 + 1] = make_float4(g[4] * di, g[5] * di, g[6] * di, g[7] * di);
}

// ---------- layer-2 epilogue: merge partials + self-loop + bias, pool ----------
__global__ void k_out(const float* __restrict__ partial, const float* __restrict__ g2,
                      const float* __restrict__ dinv, const float* __restrict__ b2,
                      const int* __restrict__ batch, float* __restrict__ gsum) {
  __shared__ float gpool[64 * 8];
  __shared__ float bb2[8];
  __shared__ int batch0s;
  int blk = blockIdx.x, tid = threadIdx.x;        // 512 threads
  for (int i = tid; i < 64 * 8; i += 512) gpool[i] = 0.f;
  if (tid < 8) bb2[tid] = b2[tid];
  if (tid == 0) {
    int n0 = blk * DBLK;
    batch0s = batch[n0 < N_NODES ? n0 : (N_NODES - 1)];
  }
  __syncthreads();
  int n = blk * DBLK + tid;
  int batch0 = batch0s;
  if (n < N_NODES) {
    float di = dinv[n];
    int gid = batch[n], goff = gid - batch0;
#pragma unroll
    for (int c = 0; c < 8; c++) {
      float s = g2[n * 8 + c];
#pragma unroll
      for (int p = 0; p < SPLIT; p++) s += partial[((size_t)p * NPAD + n) * 8 + c];
      float val = di * s + bb2[c];
      if (goff < 64) atomicAdd(&gpool[goff * 8 + c], val);
      else           unsafeAtomicAdd(&gsum[gid * 8 + c], val);
    }
  }
  __syncthreads();
  for (int i = tid; i < 64 * 8; i += 512) {
    int gid = batch0 + (i >> 3);
    float v = gpool[i];
    if (gid < N_GRAPHS && v != 0.f) unsafeAtomicAdd(&gsum[gid * 8 + (i & 7)], v);
  }
}

// ---------- mean divide (batch sorted -> binary search for counts) ----------
__global__ void k_final(const float* __restrict__ gsum, const int* __restrict__ batch,
                        float* __restrict__ out) {
  int i = blockIdx.x * 256 + threadIdx.x;
  if (i >= N_GRAPHS * 8) return;
  int g = i >> 3;
  int lo = 0, hi = N_NODES;
  while (lo < hi) { int m = (lo + hi) >> 1; if (batch[m] < g) lo = m + 1; else hi = m; }
  int lo2 = lo, hi2 = N_NODES;
  while (lo2 < hi2) { int m = (lo2 + hi2) >> 1; if (batch[m] <= g) lo2 = m + 1; else hi2 = m; }
  float c = (float)(lo2 - lo);
  out[i] = gsum[i] / fmaxf(c, 1.f);
}

extern "C" void kernel_launch(void* const* d_in, const int* in_sizes, int n_in,
                              void* d_out, int out_size, void* d_ws, size_t ws_size,
                              hipStream_t stream) {
  const float* x    = (const float*)d_in[0];
  const int* ei     = (const int*)d_in[1];
  const int* batch  = (const int*)d_in[2];
  const float* W1   = (const float*)d_in[3];
  const float* b1   = (const float*)d_in[4];
  const float* W2   = (const float*)d_in[5];
  const float* b2   = (const float*)d_in[6];
  const int* srcp = ei;
  const int* dstp = ei + N_EDGES;
  float* out = (float*)d_out;

  // workspace carve (~36.5 MB)
  char* base = (char*)d_ws;
  size_t o = 0;
  auto carve = [&](size_t bytes) -> char* {
    char* p = base + o;
    o += (bytes + 255) & ~(size_t)255;
    return p;
  };
  int* bcnt       = (int*)carve((size_t)NB * 4);
  int* boffs      = (int*)carve((size_t)(NB + 1) * 4);
  int* blockBase  = (int*)carve((size_t)FILL_BLOCKS * NB * 4);
  // stage1 (12.8 MB) and partial (SPLIT*NPAD*8*4 = 12.85 MB) time-share one region:
  // stage1 dead after k_prep; partial first written by k_aggt<5>.
  char* region    = carve((size_t)SPLIT * NPAD * 8 * 4);
  unsigned* stage1 = (unsigned*)region;
  float* partial   = (float*)region;
  unsigned* stage2 = (unsigned*)carve((size_t)N_EDGES * 4);
  int* toffs      = (int*)carve((size_t)(NBD * NSS + 1) * 4);
  float* dinv     = (float*)carve((size_t)N_NODES * 4);
  float* xd8      = (float*)carve((size_t)N_NODES * 8 * 4);
  float* g2       = (float*)carve((size_t)N_NODES * 8 * 4);
  float* gsum     = (float*)carve((size_t)N_GRAPHS * 8 * 4);

  hipMemsetAsync(bcnt, 0, (size_t)NB * 4, stream);
  hipMemsetAsync(gsum, 0, (size_t)N_GRAPHS * 8 * 4, stream);

  k_count<<<FILL_BLOCKS, 256, 0, stream>>>(dstp, bcnt, blockBase);
  k_bscan<<<1, 512, 0, stream>>>(bcnt, boffs);
  k_fill<<<FILL_BLOCKS, 256, 0, stream>>>(srcp, dstp, boffs, blockBase, stage1);
  k_sort2<<<NBD, 256, 0, stream>>>(stage1, boffs, stage2, toffs);
  k_prep<<<NB, 256, 0, stream>>>(stage1, boffs, x, dinv, xd8);
  k_aggt<5><<<NBD * SPLIT, 256, 0, stream>>>(stage2, toffs, xd8, partial);
  k_mlp<<<(N_NODES + 255) / 256, 256, 0, stream>>>(partial, xd8, dinv, W1, b1, W2, g2);
  k_aggt<8><<<NBD * SPLIT, 256, 0, stream>>>(stage2, toffs, g2, partial);
  k_out<<<NBD, 512, 0, stream>>>(partial, g2, dinv, b2, batch, gsum);
  k_final<<<64, 256, 0, stream>>>(gsum, batch, out);
}

// Round 11
// 491.736 us; speedup vs baseline: 1.2216x; 1.2216x over previous
//
#include <hip/hip_runtime.h>

#define N_NODES 100000
#define N_EDGES 3200000
#define N_GRAPHS 2048
#define BSH 6                       // phase-1: 64 dst nodes per bucket
#define BSZ 64
#define NB 1563                     // ceil(100000/64)
#define FILL_BLOCKS 512
#define CHUNK 6250                  // N_EDGES / FILL_BLOCKS
#define SBK 52                      // buckets per superblock
#define DBLK 3328                   // 52*64 dst nodes per superblock
#define NSB 31                      // ceil(1563/52)
#define NSS 196                     // src slices of 512
#define NPAD2 (NSB * DBLK)          // 103168
#define SPLIT 8
#define AGG_LDS (DBLK * 9 * 4 + 2 * 512 * 8 * 4)   // 119808 + 32768 = 152576 B

__device__ __forceinline__ void gAtomAdd(float* p, float v) { unsafeAtomicAdd(p, v); }

// ---------- phase 1: bucket sort by dst (proven) ----------
__global__ void k_count(const int* __restrict__ dst, int* __restrict__ bcnt,
                        int* __restrict__ blockBase) {
  __shared__ int hist[NB];
  int tid = threadIdx.x, blk = blockIdx.x;
  for (int i = tid; i < NB; i += 256) hist[i] = 0;
  __syncthreads();
  int beg = blk * CHUNK, end = beg + CHUNK;
  for (int e = beg + tid; e < end; e += 256) atomicAdd(&hist[dst[e] >> BSH], 1);
  __syncthreads();
  for (int i = tid; i < NB; i += 256) {
    int h = hist[i];
    if (h) blockBase[blk * NB + i] = atomicAdd(&bcnt[i], h);
  }
}

__global__ void k_bscan(const int* __restrict__ bcnt, int* __restrict__ boffs) {
  __shared__ int sh[512];
  __shared__ int carry;
  int tid = threadIdx.x;
  if (tid == 0) carry = 0;
  __syncthreads();
  for (int c = 0; c < NB; c += 512) {
    int i = c + tid;
    int v = (i < NB) ? bcnt[i] : 0;
    sh[tid] = v;
    __syncthreads();
    for (int off = 1; off < 512; off <<= 1) {
      int t = (tid >= off) ? sh[tid - off] : 0;
      __syncthreads();
      sh[tid] += t;
      __syncthreads();
    }
    if (i < NB) boffs[i] = carry + sh[tid] - v;
    __syncthreads();
    if (tid == 511) carry += sh[511];
    __syncthreads();
  }
  if (tid == 0) boffs[NB] = N_EDGES;
}

__global__ void k_fill(const int* __restrict__ src, const int* __restrict__ dst,
                       const int* __restrict__ boffs, const int* __restrict__ blockBase,
                       unsigned* __restrict__ stage1) {
  __shared__ int lbase[NB];
  int tid = threadIdx.x, blk = blockIdx.x;
  for (int i = tid; i < NB; i += 256) lbase[i] = boffs[i] + blockBase[blk * NB + i];
  __syncthreads();
  int beg = blk * CHUNK, end = beg + CHUNK;
  for (int e = beg + tid; e < end; e += 256) {
    int d = dst[e], s = src[e];
    int pos = atomicAdd(&lbase[d >> BSH], 1);
    stage1[pos] = ((unsigned)s << BSH) | (unsigned)(d & (BSZ - 1));  // src:17 | dstloc:6
  }
}

// ---------- phase 2: per superblock, sort edges by src-slice ----------
__global__ void k_sort2(const unsigned* __restrict__ stage1, const int* __restrict__ boffs,
                        unsigned* __restrict__ stage2, int* __restrict__ toffs) {
  __shared__ int hist[NSS], curs[NSS], sc[256];
  int sb = blockIdx.x, tid = threadIdx.x;          // 1024 threads
  int b0 = sb * SBK, b1 = b0 + SBK; if (b1 > NB) b1 = NB;
  int segbeg = boffs[b0], segend = boffs[b1];
  for (int i = tid; i < NSS; i += 1024) hist[i] = 0;
  __syncthreads();
  for (int k = segbeg + tid; k < segend; k += 1024)
    atomicAdd(&hist[stage1[k] >> 15], 1);          // slice = (src>>9), src = u>>6
  __syncthreads();
  int v = 0;
  if (tid < 256) { v = (tid < NSS) ? hist[tid] : 0; sc[tid] = v; }
  __syncthreads();
  for (int off = 1; off < 256; off <<= 1) {
    int add = (tid < 256 && tid >= off) ? sc[tid - off] : 0;
    __syncthreads();
    if (tid < 256) sc[tid] += add;
    __syncthreads();
  }
  if (tid < NSS) {
    int o = segbeg + sc[tid] - v;                  // exclusive
    curs[tid] = o;
    toffs[sb * NSS + tid] = o;
  }
  if (sb == NSB - 1 && tid == 0) toffs[NSB * NSS] = N_EDGES;
  __syncthreads();
  for (int bi = b0; bi < b1; bi++) {
    int kb = boffs[bi], ke = boffs[bi + 1];
    int dbase = bi * BSZ - sb * DBLK;              // local dst base, [0,DBLK)
    for (int k = kb + tid; k < ke; k += 1024) {
      unsigned u = stage1[k];
      int s = u >> BSH;
      int dl = dbase + (int)(u & (BSZ - 1));
      int pos = atomicAdd(&curs[s >> 9], 1);
      stage2[pos] = ((unsigned)(s & 511) << 12) | (unsigned)dl;   // srcloc:9 | dstloc:12
    }
  }
}

// ---------- dinv + padded xd8 = x*dinv (proven) ----------
__global__ void k_prep(const unsigned* __restrict__ stage1, const int* __restrict__ boffs,
                       const float* __restrict__ x, float* __restrict__ dinv,
                       float* __restrict__ xd8) {
  __shared__ int cnt[BSZ];
  int b = blockIdx.x, tid = threadIdx.x;
  if (tid < BSZ) cnt[tid] = 0;
  __syncthreads();
  int beg = boffs[b], end = boffs[b + 1];
  for (int k = beg + tid; k < end; k += 256) atomicAdd(&cnt[stage1[k] & (BSZ - 1)], 1);
  __syncthreads();
  int node = b * BSZ + tid;
  if (tid < BSZ && node < N_NODES) {
    float di = rsqrtf((float)(cnt[tid] + 1));      // +1 self-loop
    dinv[node] = di;
    float r[5];
#pragma unroll
    for (int c = 0; c < 5; c++) r[c] = x[node * 5 + c] * di;
    float4* xv = (float4*)xd8;
    xv[node * 2]     = make_float4(r[0], r[1], r[2], r[3]);
    xv[node * 2 + 1] = make_float4(r[4], 0.f, 0.f, 0.f);
  }
}

// ---------- tiled aggregation: big-DBLK acc + double-buffered slice stream ----------
template <int NC>
__global__ void k_aggt(const unsigned* __restrict__ stage2, const int* __restrict__ toffs,
                       const float* __restrict__ tab, float* __restrict__ partial) {
  extern __shared__ float lds[];
  float* acc = lds;                                // DBLK*9
  float* bufs = lds + DBLK * 9;                    // 2 x 512*8
  int bx = blockIdx.x;
  int sb = bx / SPLIT, p = bx % SPLIT;
  int tid = threadIdx.x;                           // 512 threads
  for (int i = tid; i < DBLK * 9; i += 512) acc[i] = 0.f;

  int nsl = (NSS - p + SPLIT - 1) / SPLIT;         // slices this split handles
  float4 r0, r1;
  {                                                 // prologue: issue slice 0 loads
    int t0 = p, base = t0 << 9;
    int ra = base + (tid >> 1), rb = base + ((tid + 512) >> 1);
    int ha = tid & 1, hb = (tid + 512) & 1;
    r0 = (ra < N_NODES) ? ((const float4*)(tab + (size_t)ra * 8))[ha] : make_float4(0, 0, 0, 0);
    r1 = (rb < N_NODES) ? ((const float4*)(tab + (size_t)rb * 8))[hb] : make_float4(0, 0, 0, 0);
  }
  for (int si = 0; si < nsl; si++) {
    int t = p + si * SPLIT;
    float* buf = bufs + (si & 1) * 4096;
    __syncthreads();                               // prior readers of this buf done
    ((float4*)buf)[tid] = r0;                      // waits vmcnt automatically
    ((float4*)buf)[tid + 512] = r1;
    __syncthreads();                               // slice visible
    if (si + 1 < nsl) {                            // issue next slice (overlaps processing)
      int tn = t + SPLIT, base = tn << 9;
      int ra = base + (tid >> 1), rb = base + ((tid + 512) >> 1);
      int ha = tid & 1, hb = (tid + 512) & 1;
      r0 = (ra < N_NODES) ? ((const float4*)(tab + (size_t)ra * 8))[ha] : make_float4(0, 0, 0, 0);
      r1 = (rb < N_NODES) ? ((const float4*)(tab + (size_t)rb * 8))[hb] : make_float4(0, 0, 0, 0);
    }
    int beg = toffs[sb * NSS + t], end = toffs[sb * NSS + t + 1];
    for (int k = beg + tid; k < end; k += 512) {
      unsigned u = stage2[k];
      const float* sp = buf + (u >> 12) * 8;
      float* ap = acc + (u & 4095) * 9;
      float4 a = ((const float4*)sp)[0];
      atomicAdd(ap + 0, a.x); atomicAdd(ap + 1, a.y);
      atomicAdd(ap + 2, a.z); atomicAdd(ap + 3, a.w);
      if (NC == 5) {
        atomicAdd(ap + 4, sp[4]);
      } else {
        float4 b = ((const float4*)sp)[1];
        atomicAdd(ap + 4, b.x); atomicAdd(ap + 5, b.y);
        atomicAdd(ap + 6, b.z); atomicAdd(ap + 7, b.w);
      }
    }
  }
  __syncthreads();
  float* pp = partial + ((size_t)p * NPAD2 + (size_t)sb * DBLK) * 8;
  for (int i = tid; i < DBLK * 8; i += 512)
    pp[i] = acc[(i >> 3) * 9 + (i & 7)];
}

// ---------- layer-1 epilogue: merge partials + self-loop, fused MLP -> g2 ----------
__global__ void k_mlp(const float* __restrict__ partial, const float* __restrict__ xd8,
                      const float* __restrict__ dinv, const float* __restrict__ W1,
                      const float* __restrict__ b1, const float* __restrict__ W2,
                      float* __restrict__ g2) {
  __shared__ float w1[150], bb1[30], w2[240];
  int tid = threadIdx.x;
  for (int i = tid; i < 150; i += 256) w1[i] = W1[i];
  for (int i = tid; i < 30; i += 256) bb1[i] = b1[i];
  for (int i = tid; i < 240; i += 256) w2[i] = W2[i];
  __syncthreads();
  int n = blockIdx.x * 256 + tid;
  if (n >= N_NODES) return;
  float di = dinv[n];
  float4 s03 = ((const float4*)xd8)[n * 2];
  float s4v = xd8[n * 8 + 4];
#pragma unroll
  for (int p = 0; p < SPLIT; p++) {
    const float* pp = partial + ((size_t)p * NPAD2 + n) * 8;
    float4 q = ((const float4*)pp)[0];
    s03.x += q.x; s03.y += q.y; s03.z += q.z; s03.w += q.w;
    s4v += pp[4];
  }
  float t[5] = {s03.x * di, s03.y * di, s03.z * di, s03.w * di, s4v * di};
  float h[30];
#pragma unroll
  for (int j = 0; j < 30; j++) h[j] = bb1[j];
#pragma unroll
  for (int k = 0; k < 5; k++)
#pragma unroll
    for (int j = 0; j < 30; j++) h[j] += t[k] * w1[k * 30 + j];
  float g[8] = {0, 0, 0, 0, 0, 0, 0, 0};
#pragma unroll
  for (int j = 0; j < 30; j++) {
    float hj = fmaxf(h[j], 0.f);
#pragma unroll
    for (int c = 0; c < 8; c++) g[c] += hj * w2[j * 8 + c];
  }
  float4* gv = (float4*)g2;
  gv[n * 2]     = make_float4(g[0] * di, g[1] * di, g[2] * di, g[3] * di);
  gv[n * 2 + 1] = make_float4(g[4] * di, g[5] * di, g[6] * di, g[7] * di);
}

// ---------- layer-2 epilogue: merge partials + self-loop + bias, pool ----------
__global__ void k_out(const float* __restrict__ partial, const float* __restrict__ g2,
                      const float* __restrict__ dinv, const float* __restrict__ b2,
                      const int* __restrict__ batch, float* __restrict__ gsum) {
  __shared__ float gpool[64 * 8];
  __shared__ float bb2[8];
  __shared__ int batch0s;
  int blk = blockIdx.x, tid = threadIdx.x;         // 512 threads
  for (int i = tid; i < 64 * 8; i += 512) gpool[i] = 0.f;
  if (tid < 8) bb2[tid] = b2[tid];
  if (tid == 0) {
    int n0 = blk * 512;
    batch0s = batch[n0 < N_NODES ? n0 : (N_NODES - 1)];
  }
  __syncthreads();
  int n = blk * 512 + tid;
  int batch0 = batch0s;
  if (n < N_NODES) {
    float di = dinv[n];
    int gid = batch[n], goff = gid - batch0;
    float4 s03 = ((const float4*)g2)[n * 2];
    float4 s47 = ((const float4*)g2)[n * 2 + 1];
#pragma unroll
    for (int p = 0; p < SPLIT; p++) {
      const float4* pp = (const float4*)(partial + ((size_t)p * NPAD2 + n) * 8);
      float4 qa = pp[0], qb = pp[1];
      s03.x += qa.x; s03.y += qa.y; s03.z += qa.z; s03.w += qa.w;
      s47.x += qb.x; s47.y += qb.y; s47.z += qb.z; s47.w += qb.w;
    }
    float val[8] = {di * s03.x + bb2[0], di * s03.y + bb2[1], di * s03.z + bb2[2],
                    di * s03.w + bb2[3], di * s47.x + bb2[4], di * s47.y + bb2[5],
                    di * s47.z + bb2[6], di * s47.w + bb2[7]};
#pragma unroll
    for (int c = 0; c < 8; c++) {
      if (goff < 64) atomicAdd(&gpool[goff * 8 + c], val[c]);
      else           gAtomAdd(&gsum[gid * 8 + c], val[c]);
    }
  }
  __syncthreads();
  for (int i = tid; i < 64 * 8; i += 512) {
    int gid = batch0 + (i >> 3);
    float v = gpool[i];
    if (gid < N_GRAPHS && v != 0.f) gAtomAdd(&gsum[gid * 8 + (i & 7)], v);
  }
}

// ---------- mean divide ----------
__global__ void k_final(const float* __restrict__ gsum, const int* __restrict__ batch,
                        float* __restrict__ out) {
  int i = blockIdx.x * 256 + threadIdx.x;
  if (i >= N_GRAPHS * 8) return;
  int g = i >> 3;
  int lo = 0, hi = N_NODES;
  while (lo < hi) { int m = (lo + hi) >> 1; if (batch[m] < g) lo = m + 1; else hi = m; }
  int lo2 = lo, hi2 = N_NODES;
  while (lo2 < hi2) { int m = (lo2 + hi2) >> 1; if (batch[m] <= g) lo2 = m + 1; else hi2 = m; }
  float c = (float)(lo2 - lo);
  out[i] = gsum[i] / fmaxf(c, 1.f);
}

extern "C" void kernel_launch(void* const* d_in, const int* in_sizes, int n_in,
                              void* d_out, int out_size, void* d_ws, size_t ws_size,
                              hipStream_t stream) {
  const float* x    = (const float*)d_in[0];
  const int* ei     = (const int*)d_in[1];
  const int* batch  = (const int*)d_in[2];
  const float* W1   = (const float*)d_in[3];
  const float* b1   = (const float*)d_in[4];
  const float* W2   = (const float*)d_in[5];
  const float* b2   = (const float*)d_in[6];
  const int* srcp = ei;
  const int* dstp = ei + N_EDGES;
  float* out = (float*)d_out;

  // workspace carve (~46.3 MB; partial overlays blockBase+stage1)
  char* base = (char*)d_ws;
  size_t o = 0;
  auto carve = [&](size_t bytes) -> char* {
    char* p = base + o;
    o += (bytes + 255) & ~(size_t)255;
    return p;
  };
  size_t partial_sz = (size_t)SPLIT * NPAD2 * 8 * 4;       // 26,411,008
  char* region     = carve(partial_sz);
  int* blockBase   = (int*)region;                          // 3.2 MB, dead after k_fill
  unsigned* stage1 = (unsigned*)(region + (size_t)FILL_BLOCKS * NB * 4); // 12.8 MB, dead after k_prep
  float* partial   = (float*)region;                        // written first by k_aggt<5>
  int* bcnt        = (int*)carve((size_t)NB * 4);
  int* boffs       = (int*)carve((size_t)(NB + 1) * 4);
  int* toffs       = (int*)carve((size_t)(NSB * NSS + 1) * 4);
  unsigned* stage2 = (unsigned*)carve((size_t)N_EDGES * 4);
  float* dinv      = (float*)carve((size_t)N_NODES * 4);
  float* xd8       = (float*)carve((size_t)N_NODES * 8 * 4);
  float* g2        = (float*)carve((size_t)N_NODES * 8 * 4);
  float* gsum      = (float*)carve((size_t)N_GRAPHS * 8 * 4);

  hipFuncSetAttribute(reinterpret_cast<const void*>(&k_aggt<5>),
                      hipFuncAttributeMaxDynamicSharedMemorySize, AGG_LDS);
  hipFuncSetAttribute(reinterpret_cast<const void*>(&k_aggt<8>),
                      hipFuncAttributeMaxDynamicSharedMemorySize, AGG_LDS);

  hipMemsetAsync(bcnt, 0, (size_t)NB * 4, stream);
  hipMemsetAsync(gsum, 0, (size_t)N_GRAPHS * 8 * 4, stream);

  k_count<<<FILL_BLOCKS, 256, 0, stream>>>(dstp, bcnt, blockBase);
  k_bscan<<<1, 512, 0, stream>>>(bcnt, boffs);
  k_fill<<<FILL_BLOCKS, 256, 0, stream>>>(srcp, dstp, boffs, blockBase, stage1);
  k_sort2<<<NSB, 1024, 0, stream>>>(stage1, boffs, stage2, toffs);
  k_prep<<<NB, 256, 0, stream>>>(stage1, boffs, x, dinv, xd8);
  k_aggt<5><<<NSB * SPLIT, 512, AGG_LDS, stream>>>(stage2, toffs, xd8, partial);
  k_mlp<<<(N_NODES + 255) / 256, 256, 0, stream>>>(partial, xd8, dinv, W1, b1, W2, g2);
  k_aggt<8><<<NSB * SPLIT, 512, AGG_LDS, stream>>>(stage2, toffs, g2, partial);
  k_out<<<(N_NODES + 511) / 512, 512, 0, stream>>>(partial, g2, dinv, b2, batch, gsum);
  k_final<<<64, 256, 0, stream>>>(gsum, batch, out);
}

// Round 12
// 210.704 us; speedup vs baseline: 2.8509x; 2.3338x over previous
//
#include <hip/hip_runtime.h>

#define N_NODES 100000
#define N_EDGES 3200000
#define N_GRAPHS 2048
#define BSH 6                       // 64 dst nodes per bucket
#define BSZ 64
#define NB 1563                     // ceil(100000/64)
#define FILL_BLOCKS 512
#define CHUNK 6250                  // N_EDGES / FILL_BLOCKS

__device__ __forceinline__ void gAtomAdd(float* p, float v) { unsafeAtomicAdd(p, v); }

// ---------- phase 1: bucket sort by dst (proven) ----------
__global__ void k_count(const int* __restrict__ dst, int* __restrict__ bcnt,
                        int* __restrict__ blockBase) {
  __shared__ int hist[NB];
  int tid = threadIdx.x, blk = blockIdx.x;
  for (int i = tid; i < NB; i += 256) hist[i] = 0;
  __syncthreads();
  int beg = blk * CHUNK, end = beg + CHUNK;
  for (int e = beg + tid; e < end; e += 256) atomicAdd(&hist[dst[e] >> BSH], 1);
  __syncthreads();
  for (int i = tid; i < NB; i += 256) {
    int h = hist[i];
    if (h) blockBase[blk * NB + i] = atomicAdd(&bcnt[i], h);
  }
}

__global__ void k_bscan(const int* __restrict__ bcnt, int* __restrict__ boffs) {
  __shared__ int sh[512];
  __shared__ int carry;
  int tid = threadIdx.x;
  if (tid == 0) carry = 0;
  __syncthreads();
  for (int c = 0; c < NB; c += 512) {
    int i = c + tid;
    int v = (i < NB) ? bcnt[i] : 0;
    sh[tid] = v;
    __syncthreads();
    for (int off = 1; off < 512; off <<= 1) {
      int t = (tid >= off) ? sh[tid - off] : 0;
      __syncthreads();
      sh[tid] += t;
      __syncthreads();
    }
    if (i < NB) boffs[i] = carry + sh[tid] - v;
    __syncthreads();
    if (tid == 511) carry += sh[511];
    __syncthreads();
  }
  if (tid == 0) boffs[NB] = N_EDGES;
}

__global__ void k_fill(const int* __restrict__ src, const int* __restrict__ dst,
                       const int* __restrict__ boffs, const int* __restrict__ blockBase,
                       unsigned* __restrict__ stage1) {
  __shared__ int lbase[NB];
  int tid = threadIdx.x, blk = blockIdx.x;
  for (int i = tid; i < NB; i += 256) lbase[i] = boffs[i] + blockBase[blk * NB + i];
  __syncthreads();
  int beg = blk * CHUNK, end = beg + CHUNK;
  for (int e = beg + tid; e < end; e += 256) {
    int d = dst[e], s = src[e];
    int pos = atomicAdd(&lbase[d >> BSH], 1);
    stage1[pos] = ((unsigned)s << BSH) | (unsigned)(d & (BSZ - 1));  // src:17 | dstloc:6
  }
}

// ---------- phase 2a: per-node offsets (noffs) + dinv + xd8 ----------
__global__ void k_prep2(const unsigned* __restrict__ stage1, const int* __restrict__ boffs,
                        const float* __restrict__ x, int* __restrict__ noffs,
                        float* __restrict__ dinv, float* __restrict__ xd8) {
  __shared__ int cnt[BSZ];
  __shared__ int sc[BSZ];
  int b = blockIdx.x, tid = threadIdx.x;
  if (tid < BSZ) cnt[tid] = 0;
  __syncthreads();
  int beg = boffs[b], end = boffs[b + 1];
  for (int k = beg + tid; k < end; k += 256) atomicAdd(&cnt[stage1[k] & (BSZ - 1)], 1);
  __syncthreads();
  if (tid < BSZ) sc[tid] = cnt[tid];
  __syncthreads();
  for (int off = 1; off < BSZ; off <<= 1) {       // inclusive scan over 64
    int t = (tid < BSZ && tid >= off) ? sc[tid - off] : 0;
    __syncthreads();
    if (tid < BSZ) sc[tid] += t;
    __syncthreads();
  }
  if (tid < BSZ) {
    int node = b * BSZ + tid;
    if (node <= N_NODES) noffs[node] = beg + sc[tid] - cnt[tid];   // exclusive
    if (node < N_NODES) {
      float di = rsqrtf((float)(cnt[tid] + 1));   // +1 self-loop
      dinv[node] = di;
      float r[5];
#pragma unroll
      for (int c = 0; c < 5; c++) r[c] = x[node * 5 + c] * di;
      float4* xv = (float4*)xd8;
      xv[node * 2]     = make_float4(r[0], r[1], r[2], r[3]);
      xv[node * 2 + 1] = make_float4(r[4], 0.f, 0.f, 0.f);
    }
  }
}

// ---------- phase 2b: scatter into per-node contiguous runs ----------
__global__ void k_fill2(const unsigned* __restrict__ stage1, const int* __restrict__ boffs,
                        const int* __restrict__ noffs, int* __restrict__ csr) {
  __shared__ int curs[BSZ];
  int b = blockIdx.x, tid = threadIdx.x;
  if (tid < BSZ) {
    int node = b * BSZ + tid;
    curs[tid] = (node < N_NODES) ? noffs[node] : N_EDGES;
  }
  __syncthreads();
  int beg = boffs[b], end = boffs[b + 1];
  for (int k = beg + tid; k < end; k += 256) {
    unsigned u = stage1[k];
    int pos = atomicAdd(&curs[u & (BSZ - 1)], 1);
    csr[pos] = (int)(u >> BSH);
  }
}

// ---------- layer-1: per-node register accumulation + fused MLP ----------
__global__ void k_agg1(const int* __restrict__ csr, const int* __restrict__ noffs,
                       const float* __restrict__ xd8, const float* __restrict__ dinv,
                       const float* __restrict__ W1, const float* __restrict__ b1,
                       const float* __restrict__ W2, float* __restrict__ g2) {
  __shared__ float w1[150], bb1[30], w2[240];
  int tid = threadIdx.x;
  for (int i = tid; i < 150; i += 256) w1[i] = W1[i];
  for (int i = tid; i < 30; i += 256) bb1[i] = b1[i];
  for (int i = tid; i < 240; i += 256) w2[i] = W2[i];
  __syncthreads();
  int n = blockIdx.x * 256 + tid;
  if (n >= N_NODES) return;
  const float4* xv = (const float4*)xd8;
  float a0 = 0, a1 = 0, a2 = 0, a3 = 0, a4 = 0;
  int k = noffs[n], end = noffs[n + 1];
  for (; k + 4 <= end; k += 4) {                  // 8 independent loads in flight
    int s0 = csr[k], s1 = csr[k + 1], s2 = csr[k + 2], s3 = csr[k + 3];
    float4 q0 = xv[s0 * 2], q1 = xv[s1 * 2], q2 = xv[s2 * 2], q3 = xv[s3 * 2];
    float c0 = xd8[s0 * 8 + 4], c1 = xd8[s1 * 8 + 4], c2 = xd8[s2 * 8 + 4], c3 = xd8[s3 * 8 + 4];
    a0 += q0.x + q1.x + q2.x + q3.x;
    a1 += q0.y + q1.y + q2.y + q3.y;
    a2 += q0.z + q1.z + q2.z + q3.z;
    a3 += q0.w + q1.w + q2.w + q3.w;
    a4 += c0 + c1 + c2 + c3;
  }
  for (; k < end; k++) {
    int s = csr[k];
    float4 q = xv[s * 2];
    a0 += q.x; a1 += q.y; a2 += q.z; a3 += q.w; a4 += xd8[s * 8 + 4];
  }
  float di = dinv[n];
  float t[5] = {(a0 + xd8[n * 8 + 0]) * di, (a1 + xd8[n * 8 + 1]) * di,
                (a2 + xd8[n * 8 + 2]) * di, (a3 + xd8[n * 8 + 3]) * di,
                (a4 + xd8[n * 8 + 4]) * di};
  float h[30];
#pragma unroll
  for (int j = 0; j < 30; j++) h[j] = bb1[j];
#pragma unroll
  for (int kk = 0; kk < 5; kk++)
#pragma unroll
    for (int j = 0; j < 30; j++) h[j] += t[kk] * w1[kk * 30 + j];
  float g[8] = {0, 0, 0, 0, 0, 0, 0, 0};
#pragma unroll
  for (int j = 0; j < 30; j++) {
    float hj = fmaxf(h[j], 0.f);
#pragma unroll
    for (int c = 0; c < 8; c++) g[c] += hj * w2[j * 8 + c];
  }
  float4* gv = (float4*)g2;
  gv[n * 2]     = make_float4(g[0] * di, g[1] * di, g[2] * di, g[3] * di);
  gv[n * 2 + 1] = make_float4(g[4] * di, g[5] * di, g[6] * di, g[7] * di);
}

// ---------- layer-2: per-node register accumulation + fused pooling ----------
__global__ void k_agg2(const int* __restrict__ csr, const int* __restrict__ noffs,
                       const float* __restrict__ g2, const float* __restrict__ dinv,
                       const float* __restrict__ b2, const int* __restrict__ batch,
                       float* __restrict__ gsum) {
  __shared__ float gpool[64 * 8];
  __shared__ float bb2[8];
  __shared__ int batch0s;
  int blk = blockIdx.x, tid = threadIdx.x;
  for (int i = tid; i < 64 * 8; i += 256) gpool[i] = 0.f;
  if (tid < 8) bb2[tid] = b2[tid];
  if (tid == 0) {
    int n0 = blk * 256;
    batch0s = batch[n0 < N_NODES ? n0 : (N_NODES - 1)];
  }
  __syncthreads();
  int n = blk * 256 + tid;
  int batch0 = batch0s;
  if (n < N_NODES) {
    const float4* gv = (const float4*)g2;
    float4 lo = make_float4(0, 0, 0, 0), hi = make_float4(0, 0, 0, 0);
    int k = noffs[n], end = noffs[n + 1];
    for (; k + 2 <= end; k += 2) {                // 4 independent loads in flight
      int s0 = csr[k], s1 = csr[k + 1];
      float4 p0 = gv[s0 * 2], q0 = gv[s0 * 2 + 1];
      float4 p1 = gv[s1 * 2], q1 = gv[s1 * 2 + 1];
      lo.x += p0.x + p1.x; lo.y += p0.y + p1.y;
      lo.z += p0.z + p1.z; lo.w += p0.w + p1.w;
      hi.x += q0.x + q1.x; hi.y += q0.y + q1.y;
      hi.z += q0.z + q1.z; hi.w += q0.w + q1.w;
    }
    for (; k < end; k++) {
      int s = csr[k];
      float4 p = gv[s * 2], q = gv[s * 2 + 1];
      lo.x += p.x; lo.y += p.y; lo.z += p.z; lo.w += p.w;
      hi.x += q.x; hi.y += q.y; hi.z += q.z; hi.w += q.w;
    }
    float di = dinv[n];
    float4 sl = gv[n * 2], sh = gv[n * 2 + 1];    // self-loop
    float val[8] = {di * (lo.x + sl.x) + bb2[0], di * (lo.y + sl.y) + bb2[1],
                    di * (lo.z + sl.z) + bb2[2], di * (lo.w + sl.w) + bb2[3],
                    di * (hi.x + sh.x) + bb2[4], di * (hi.y + sh.y) + bb2[5],
                    di * (hi.z + sh.z) + bb2[6], di * (hi.w + sh.w) + bb2[7]};
    int gid = batch[n], goff = gid - batch0;
#pragma unroll
    for (int c = 0; c < 8; c++) {
      if (goff < 64) atomicAdd(&gpool[goff * 8 + c], val[c]);
      else           gAtomAdd(&gsum[gid * 8 + c], val[c]);
    }
  }
  __syncthreads();
  for (int i = tid; i < 64 * 8; i += 256) {
    int gid = batch0 + (i >> 3);
    float v = gpool[i];
    if (gid < N_GRAPHS && v != 0.f) gAtomAdd(&gsum[gid * 8 + (i & 7)], v);
  }
}

// ---------- mean divide ----------
__global__ void k_final(const float* __restrict__ gsum, const int* __restrict__ batch,
                        float* __restrict__ out) {
  int i = blockIdx.x * 256 + threadIdx.x;
  if (i >= N_GRAPHS * 8) return;
  int g = i >> 3;
  int lo = 0, hi = N_NODES;
  while (lo < hi) { int m = (lo + hi) >> 1; if (batch[m] < g) lo = m + 1; else hi = m; }
  int lo2 = lo, hi2 = N_NODES;
  while (lo2 < hi2) { int m = (lo2 + hi2) >> 1; if (batch[m] <= g) lo2 = m + 1; else hi2 = m; }
  float c = (float)(lo2 - lo);
  out[i] = gsum[i] / fmaxf(c, 1.f);
}

extern "C" void kernel_launch(void* const* d_in, const int* in_sizes, int n_in,
                              void* d_out, int out_size, void* d_ws, size_t ws_size,
                              hipStream_t stream) {
  const float* x    = (const float*)d_in[0];
  const int* ei     = (const int*)d_in[1];
  const int* batch  = (const int*)d_in[2];
  const float* W1   = (const float*)d_in[3];
  const float* b1   = (const float*)d_in[4];
  const float* W2   = (const float*)d_in[5];
  const float* b2   = (const float*)d_in[6];
  const int* srcp = ei;
  const int* dstp = ei + N_EDGES;
  float* out = (float*)d_out;

  // workspace carve (~36.5 MB)
  char* base = (char*)d_ws;
  size_t o = 0;
  auto carve = [&](size_t bytes) -> char* {
    char* p = base + o;
    o += (bytes + 255) & ~(size_t)255;
    return p;
  };
  int* bcnt        = (int*)carve((size_t)NB * 4);
  int* boffs       = (int*)carve((size_t)(NB + 1) * 4);
  int* blockBase   = (int*)carve((size_t)FILL_BLOCKS * NB * 4);
  unsigned* stage1 = (unsigned*)carve((size_t)N_EDGES * 4);
  int* csr         = (int*)carve((size_t)N_EDGES * 4);
  int* noffs       = (int*)carve((size_t)(N_NODES + 2) * 4);
  float* dinv      = (float*)carve((size_t)N_NODES * 4);
  float* xd8       = (float*)carve((size_t)N_NODES * 8 * 4);
  float* g2        = (float*)carve((size_t)N_NODES * 8 * 4);
  float* gsum      = (float*)carve((size_t)N_GRAPHS * 8 * 4);

  hipMemsetAsync(bcnt, 0, (size_t)NB * 4, stream);
  hipMemsetAsync(gsum, 0, (size_t)N_GRAPHS * 8 * 4, stream);

  k_count<<<FILL_BLOCKS, 256, 0, stream>>>(dstp, bcnt, blockBase);
  k_bscan<<<1, 512, 0, stream>>>(bcnt, boffs);
  k_fill<<<FILL_BLOCKS, 256, 0, stream>>>(srcp, dstp, boffs, blockBase, stage1);
  k_prep2<<<NB, 256, 0, stream>>>(stage1, boffs, x, noffs, dinv, xd8);
  k_fill2<<<NB, 256, 0, stream>>>(stage1, boffs, noffs, csr);
  k_agg1<<<(N_NODES + 255) / 256, 256, 0, stream>>>(csr, noffs, xd8, dinv, W1, b1, W2, g2);
  k_agg2<<<(N_NODES + 255) / 256, 256, 0, stream>>>(csr, noffs, g2, dinv, b2, batch, gsum);
  k_final<<<64, 256, 0, stream>>>(gsum, batch, out);
}

// Round 13
// 194.760 us; speedup vs baseline: 3.0843x; 1.0819x over previous
//
#include <hip/hip_runtime.h>

#define N_NODES 100000
#define N_EDGES 3200000
#define N_GRAPHS 2048
#define SSH 8                       // 256 dst nodes per superbucket
#define SSZ 256
#define NSB 391                     // ceil(100000/256)
#define FILL_BLOCKS 512
#define CHUNK 6250                  // N_EDGES / FILL_BLOCKS

__device__ __forceinline__ void gAtomAdd(float* p, float v) { unsafeAtomicAdd(p, v); }

// ---------- pass 1: per-block superbucket histogram + space reservation ----------
__global__ void kA_count(const int* __restrict__ dst, int* __restrict__ bcnt,
                         int* __restrict__ blockBase) {
  __shared__ int hist[NSB];
  int tid = threadIdx.x, blk = blockIdx.x;
  for (int i = tid; i < NSB; i += 256) hist[i] = 0;
  __syncthreads();
  int beg = blk * CHUNK, end = beg + CHUNK;
  for (int e = beg + tid; e < end; e += 256) atomicAdd(&hist[dst[e] >> SSH], 1);
  __syncthreads();
  for (int i = tid; i < NSB; i += 256) {
    int h = hist[i];
    if (h) blockBase[blk * NSB + i] = atomicAdd(&bcnt[i], h);
  }
}

// ---------- exclusive scan over NSB counts (single block) ----------
__global__ void k_bscan(const int* __restrict__ bcnt, int* __restrict__ sboffs) {
  __shared__ int sh[512];
  int tid = threadIdx.x;
  int v = (tid < NSB) ? bcnt[tid] : 0;
  sh[tid] = v;
  __syncthreads();
  for (int off = 1; off < 512; off <<= 1) {
    int t = (tid >= off) ? sh[tid - off] : 0;
    __syncthreads();
    sh[tid] += t;
    __syncthreads();
  }
  if (tid < NSB) sboffs[tid] = sh[tid] - v;
  if (tid == 0) sboffs[NSB] = N_EDGES;
}

// ---------- pass 2: scatter packed edges into superbucket segments ----------
// runs of ~16 entries = one 64B line -> single-writer lines, no XCD write blowup
__global__ void kB_fill(const int* __restrict__ src, const int* __restrict__ dst,
                        const int* __restrict__ sboffs, const int* __restrict__ blockBase,
                        unsigned* __restrict__ stage) {
  __shared__ int lbase[NSB];
  int tid = threadIdx.x, blk = blockIdx.x;
  for (int i = tid; i < NSB; i += 256) lbase[i] = sboffs[i] + blockBase[blk * NSB + i];
  __syncthreads();
  int beg = blk * CHUNK, end = beg + CHUNK;
  for (int e = beg + tid; e < end; e += 256) {
    int d = dst[e], s = src[e];
    int pos = atomicAdd(&lbase[d >> SSH], 1);
    stage[pos] = ((unsigned)s << SSH) | (unsigned)(d & (SSZ - 1));  // src:17 | dstloc:8
  }
}

// ---------- pass 3: per-superbucket node sort -> csr + noffs + dinv + xd8 ----------
// one block per superbucket; all csr writes land in this block's contiguous region
__global__ void kC_csr(const unsigned* __restrict__ stage, const int* __restrict__ sboffs,
                       const float* __restrict__ x, int* __restrict__ noffs,
                       float* __restrict__ dinv, float* __restrict__ xd8,
                       int* __restrict__ csr) {
  __shared__ int cnt[SSZ], sc[SSZ], cur[SSZ];
  int b = blockIdx.x, tid = threadIdx.x;
  cnt[tid] = 0;
  __syncthreads();
  int beg = sboffs[b], end = sboffs[b + 1];
  for (int k = beg + tid; k < end; k += 256) atomicAdd(&cnt[stage[k] & (SSZ - 1)], 1);
  __syncthreads();
  sc[tid] = cnt[tid];
  __syncthreads();
  for (int off = 1; off < SSZ; off <<= 1) {       // inclusive scan over 256
    int t = (tid >= off) ? sc[tid - off] : 0;
    __syncthreads();
    sc[tid] += t;
    __syncthreads();
  }
  int excl = sc[tid] - cnt[tid];
  int node = b * SSZ + tid;
  if (node <= N_NODES) noffs[node] = beg + excl;   // exclusive; node==N covers the end
  if (node < N_NODES) {
    float di = rsqrtf((float)(cnt[tid] + 1));      // +1 self-loop
    dinv[node] = di;
    float r[5];
#pragma unroll
    for (int c = 0; c < 5; c++) r[c] = x[node * 5 + c] * di;
    float4* xv = (float4*)xd8;
    xv[node * 2]     = make_float4(r[0], r[1], r[2], r[3]);
    xv[node * 2 + 1] = make_float4(r[4], 0.f, 0.f, 0.f);
  }
  cur[tid] = beg + excl;
  __syncthreads();
  for (int k = beg + tid; k < end; k += 256) {
    unsigned u = stage[k];
    int pos = atomicAdd(&cur[u & (SSZ - 1)], 1);
    csr[pos] = (int)(u >> SSH);
  }
}

// ---------- layer-1: per-node register accumulation + fused MLP (proven r12) ----------
__global__ void k_agg1(const int* __restrict__ csr, const int* __restrict__ noffs,
                       const float* __restrict__ xd8, const float* __restrict__ dinv,
                       const float* __restrict__ W1, const float* __restrict__ b1,
                       const float* __restrict__ W2, float* __restrict__ g2) {
  __shared__ float w1[150], bb1[30], w2[240];
  int tid = threadIdx.x;
  for (int i = tid; i < 150; i += 256) w1[i] = W1[i];
  for (int i = tid; i < 30; i += 256) bb1[i] = b1[i];
  for (int i = tid; i < 240; i += 256) w2[i] = W2[i];
  __syncthreads();
  int n = blockIdx.x * 256 + tid;
  if (n >= N_NODES) return;
  const float4* xv = (const float4*)xd8;
  float a0 = 0, a1 = 0, a2 = 0, a3 = 0, a4 = 0;
  int k = noffs[n], end = noffs[n + 1];
  for (; k + 4 <= end; k += 4) {
    int s0 = csr[k], s1 = csr[k + 1], s2 = csr[k + 2], s3 = csr[k + 3];
    float4 q0 = xv[s0 * 2], q1 = xv[s1 * 2], q2 = xv[s2 * 2], q3 = xv[s3 * 2];
    float c0 = xd8[s0 * 8 + 4], c1 = xd8[s1 * 8 + 4], c2 = xd8[s2 * 8 + 4], c3 = xd8[s3 * 8 + 4];
    a0 += q0.x + q1.x + q2.x + q3.x;
    a1 += q0.y + q1.y + q2.y + q3.y;
    a2 += q0.z + q1.z + q2.z + q3.z;
    a3 += q0.w + q1.w + q2.w + q3.w;
    a4 += c0 + c1 + c2 + c3;
  }
  for (; k < end; k++) {
    int s = csr[k];
    float4 q = xv[s * 2];
    a0 += q.x; a1 += q.y; a2 += q.z; a3 += q.w; a4 += xd8[s * 8 + 4];
  }
  float di = dinv[n];
  float t[5] = {(a0 + xd8[n * 8 + 0]) * di, (a1 + xd8[n * 8 + 1]) * di,
                (a2 + xd8[n * 8 + 2]) * di, (a3 + xd8[n * 8 + 3]) * di,
                (a4 + xd8[n * 8 + 4]) * di};
  float h[30];
#pragma unroll
  for (int j = 0; j < 30; j++) h[j] = bb1[j];
#pragma unroll
  for (int kk = 0; kk < 5; kk++)
#pragma unroll
    for (int j = 0; j < 30; j++) h[j] += t[kk] * w1[kk * 30 + j];
  float g[8] = {0, 0, 0, 0, 0, 0, 0, 0};
#pragma unroll
  for (int j = 0; j < 30; j++) {
    float hj = fmaxf(h[j], 0.f);
#pragma unroll
    for (int c = 0; c < 8; c++) g[c] += hj * w2[j * 8 + c];
  }
  float4* gv = (float4*)g2;
  gv[n * 2]     = make_float4(g[0] * di, g[1] * di, g[2] * di, g[3] * di);
  gv[n * 2 + 1] = make_float4(g[4] * di, g[5] * di, g[6] * di, g[7] * di);
}

// ---------- layer-2: per-node register accumulation + fused pooling (proven r12) ----------
__global__ void k_agg2(const int* __restrict__ csr, const int* __restrict__ noffs,
                       const float* __restrict__ g2, const float* __restrict__ dinv,
                       const float* __restrict__ b2, const int* __restrict__ batch,
                       float* __restrict__ gsum) {
  __shared__ float gpool[64 * 8];
  __shared__ float bb2[8];
  __shared__ int batch0s;
  int blk = blockIdx.x, tid = threadIdx.x;
  for (int i = tid; i < 64 * 8; i += 256) gpool[i] = 0.f;
  if (tid < 8) bb2[tid] = b2[tid];
  if (tid == 0) {
    int n0 = blk * 256;
    batch0s = batch[n0 < N_NODES ? n0 : (N_NODES - 1)];
  }
  __syncthreads();
  int n = blk * 256 + tid;
  int batch0 = batch0s;
  if (n < N_NODES) {
    const float4* gv = (const float4*)g2;
    float4 lo = make_float4(0, 0, 0, 0), hi = make_float4(0, 0, 0, 0);
    int k = noffs[n], end = noffs[n + 1];
    for (; k + 2 <= end; k += 2) {
      int s0 = csr[k], s1 = csr[k + 1];
      float4 p0 = gv[s0 * 2], q0 = gv[s0 * 2 + 1];
      float4 p1 = gv[s1 * 2], q1 = gv[s1 * 2 + 1];
      lo.x += p0.x + p1.x; lo.y += p0.y + p1.y;
      lo.z += p0.z + p1.z; lo.w += p0.w + p1.w;
      hi.x += q0.x + q1.x; hi.y += q0.y + q1.y;
      hi.z += q0.z + q1.z; hi.w += q0.w + q1.w;
    }
    for (; k < end; k++) {
      int s = csr[k];
      float4 p = gv[s * 2], q = gv[s * 2 + 1];
      lo.x += p.x; lo.y += p.y; lo.z += p.z; lo.w += p.w;
      hi.x += q.x; hi.y += q.y; hi.z += q.z; hi.w += q.w;
    }
    float di = dinv[n];
    float4 sl = gv[n * 2], sh = gv[n * 2 + 1];
    float val[8] = {di * (lo.x + sl.x) + bb2[0], di * (lo.y + sl.y) + bb2[1],
                    di * (lo.z + sl.z) + bb2[2], di * (lo.w + sl.w) + bb2[3],
                    di * (hi.x + sh.x) + bb2[4], di * (hi.y + sh.y) + bb2[5],
                    di * (hi.z + sh.z) + bb2[6], di * (hi.w + sh.w) + bb2[7]};
    int gid = batch[n], goff = gid - batch0;
#pragma unroll
    for (int c = 0; c < 8; c++) {
      if (goff < 64) atomicAdd(&gpool[goff * 8 + c], val[c]);
      else           gAtomAdd(&gsum[gid * 8 + c], val[c]);
    }
  }
  __syncthreads();
  for (int i = tid; i < 64 * 8; i += 256) {
    int gid = batch0 + (i >> 3);
    float v = gpool[i];
    if (gid < N_GRAPHS && v != 0.f) gAtomAdd(&gsum[gid * 8 + (i & 7)], v);
  }
}

// ---------- mean divide ----------
__global__ void k_final(const float* __restrict__ gsum, const int* __restrict__ batch,
                        float* __restrict__ out) {
  int i = blockIdx.x * 256 + threadIdx.x;
  if (i >= N_GRAPHS * 8) return;
  int g = i >> 3;
  int lo = 0, hi = N_NODES;
  while (lo < hi) { int m = (lo + hi) >> 1; if (batch[m] < g) lo = m + 1; else hi = m; }
  int lo2 = lo, hi2 = N_NODES;
  while (lo2 < hi2) { int m = (lo2 + hi2) >> 1; if (batch[m] <= g) lo2 = m + 1; else hi2 = m; }
  float c = (float)(lo2 - lo);
  out[i] = gsum[i] / fmaxf(c, 1.f);
}

extern "C" void kernel_launch(void* const* d_in, const int* in_sizes, int n_in,
                              void* d_out, int out_size, void* d_ws, size_t ws_size,
                              hipStream_t stream) {
  const float* x    = (const float*)d_in[0];
  const int* ei     = (const int*)d_in[1];
  const int* batch  = (const int*)d_in[2];
  const float* W1   = (const float*)d_in[3];
  const float* b1   = (const float*)d_in[4];
  const float* W2   = (const float*)d_in[5];
  const float* b2   = (const float*)d_in[6];
  const int* srcp = ei;
  const int* dstp = ei + N_EDGES;
  float* out = (float*)d_out;

  // workspace carve (~33 MB)
  char* base = (char*)d_ws;
  size_t o = 0;
  auto carve = [&](size_t bytes) -> char* {
    char* p = base + o;
    o += (bytes + 255) & ~(size_t)255;
    return p;
  };
  int* bcnt        = (int*)carve((size_t)NSB * 4);
  int* sboffs      = (int*)carve((size_t)(NSB + 1) * 4);
  int* blockBase   = (int*)carve((size_t)FILL_BLOCKS * NSB * 4);
  unsigned* stage  = (unsigned*)carve((size_t)N_EDGES * 4);
  int* csr         = (int*)carve((size_t)N_EDGES * 4);
  int* noffs       = (int*)carve((size_t)(N_NODES + 2) * 4);
  float* dinv      = (float*)carve((size_t)N_NODES * 4);
  float* xd8       = (float*)carve((size_t)N_NODES * 8 * 4);
  float* g2        = (float*)carve((size_t)N_NODES * 8 * 4);
  float* gsum      = (float*)carve((size_t)N_GRAPHS * 8 * 4);

  hipMemsetAsync(bcnt, 0, (size_t)NSB * 4, stream);
  hipMemsetAsync(gsum, 0, (size_t)N_GRAPHS * 8 * 4, stream);

  kA_count<<<FILL_BLOCKS, 256, 0, stream>>>(dstp, bcnt, blockBase);
  k_bscan<<<1, 512, 0, stream>>>(bcnt, sboffs);
  kB_fill<<<FILL_BLOCKS, 256, 0, stream>>>(srcp, dstp, sboffs, blockBase, stage);
  kC_csr<<<NSB, 256, 0, stream>>>(stage, sboffs, x, noffs, dinv, xd8, csr);
  k_agg1<<<(N_NODES + 255) / 256, 256, 0, stream>>>(csr, noffs, xd8, dinv, W1, b1, W2, g2);
  k_agg2<<<(N_NODES + 255) / 256, 256, 0, stream>>>(csr, noffs, g2, dinv, b2, batch, gsum);
  k_final<<<64, 256, 0, stream>>>(gsum, batch, out);
}